// Round 1
// 554.241 us; speedup vs baseline: 1.1397x; 1.1397x over previous
//
#include <hip/hip_runtime.h>

typedef unsigned short u16;
typedef unsigned int u32;
typedef __attribute__((ext_vector_type(8))) short bf16x8;
typedef __attribute__((ext_vector_type(4))) float f32x4;

__device__ __forceinline__ float bf_lo(u32 u){ return __uint_as_float(u << 16); }
__device__ __forceinline__ float bf_hi(u32 u){ return __uint_as_float(u & 0xffff0000u); }
__device__ __forceinline__ float bf2f(u16 v){ return __uint_as_float((u32)v << 16); }
__device__ __forceinline__ u16 f2bf(float f){
    u32 u = __float_as_uint(f);
    u32 r = (u + 0x7fffu + ((u >> 16) & 1u)) >> 16;
    return (u16)r;
}
__device__ __forceinline__ u32 pack2(float a, float b){
    return (u32)f2bf(a) | ((u32)f2bf(b) << 16);
}

// ======== fused: hist3+rank (returning atomic histogram) || ntgemm_M || ntgemm_H ========
__global__ __launch_bounds__(256) void fusedA_kernel(
    const int* __restrict__ d0, const int* __restrict__ d1, const int* __restrict__ d2,
    int* __restrict__ rk0, int* __restrict__ rk1, int* __restrict__ rk2,
    int E0, int E1, int E2, int b0, int b1, int b2, int n0, int n1, int n2,
    int* __restrict__ cnt, int h0, int h1, int h2,
    const float* __restrict__ Xm, const float* __restrict__ Wm,
    const float* __restrict__ bm, u16* __restrict__ Tm, int NM,
    const float* __restrict__ Xh, const float* __restrict__ Wh,
    const float* __restrict__ bh, u16* __restrict__ Th, int NH,
    int gm, int gh)
{
    int bid = blockIdx.x;
    int HB = h0 + h1 + h2;
    if (bid < HB){
        int t, lb;
        if (bid < h0){ t = 0; lb = bid; }
        else if (bid < h0 + h1){ t = 1; lb = bid - h0; }
        else { t = 2; lb = bid - h0 - h1; }
        const int* d = t == 0 ? d0 : (t == 1 ? d1 : d2);
        int* rk = t == 0 ? rk0 : (t == 1 ? rk1 : rk2);
        int E = t == 0 ? E0 : (t == 1 ? E1 : E2);
        int b = t == 0 ? b0 : (t == 1 ? b1 : b2);
        int n = t == 0 ? n0 : (t == 1 ? n1 : n2);
        int i = lb * 256 + threadIdx.x;
        if (i < E){
            int x = d[i];
            if ((unsigned)x < (unsigned)n) rk[i] = atomicAdd(&cnt[b + x], 1);
        }
        return;
    }
    bid -= HB;
    const float *A, *W, *bias; u16* C; int N, lgrid, lbid;
    if (bid < gm){ A = Xm; W = Wm; bias = bm; C = Tm; N = NM; lgrid = gm; lbid = bid; }
    else         { A = Xh; W = Wh; bias = bh; C = Th; N = NH; lgrid = gh; lbid = bid - gm; }

    int tid = threadIdx.x;
    int wave = tid >> 6, lane = tid & 63;
    int colHalf = wave & 1;
    int ln16 = lane & 15, quad = lane >> 4;

    bf16x8 Bfrag[4][4];
    #pragma unroll
    for (int t = 0; t < 4; ++t){
        int col = colHalf * 64 + t * 16 + ln16;
        #pragma unroll
        for (int q = 0; q < 4; ++q){
            bf16x8 f;
            #pragma unroll
            for (int j = 0; j < 8; ++j)
                f[j] = (short)f2bf(W[(q * 32 + quad * 8 + j) * 128 + col]);
            Bfrag[t][q] = f;
        }
    }
    float bv[4];
    #pragma unroll
    for (int t = 0; t < 4; ++t)
        bv[t] = bias[colHalf * 64 + t * 16 + ln16];

    int rowBlocks = (N + 15) >> 4;
    for (int rb = lbid * 2 + (wave >> 1); rb < rowBlocks; rb += lgrid * 2){
        int row0 = rb * 16;
        int ar = row0 + ln16; if (ar > N - 1) ar = N - 1;
        const float* Arow = A + (size_t)ar * 128 + quad * 8;
        bf16x8 Af[4];
        #pragma unroll
        for (int q = 0; q < 4; ++q){
            f32x4 lo = *(const f32x4*)(Arow + q * 32);
            f32x4 hi = *(const f32x4*)(Arow + q * 32 + 4);
            bf16x8 f;
            #pragma unroll
            for (int j = 0; j < 4; ++j){ f[j] = (short)f2bf(lo[j]); f[4+j] = (short)f2bf(hi[j]); }
            Af[q] = f;
        }
        f32x4 acc[4];
        #pragma unroll
        for (int t = 0; t < 4; ++t) acc[t] = (f32x4){bv[t], bv[t], bv[t], bv[t]};
        #pragma unroll
        for (int q = 0; q < 4; ++q)
            #pragma unroll
            for (int t = 0; t < 4; ++t)
                acc[t] = __builtin_amdgcn_mfma_f32_16x16x32_bf16(Af[q], Bfrag[t][q], acc[t], 0, 0, 0);
        #pragma unroll
        for (int t = 0; t < 4; ++t){
            int col = colHalf * 64 + t * 16 + ln16;
            #pragma unroll
            for (int r = 0; r < 4; ++r){
                int row = row0 + quad * 4 + r;
                if (row < N) C[(size_t)row * 128 + col] = f2bf(acc[t][r]);
            }
        }
    }
}

// ---------------- 3-phase device-wide exclusive scan ----------------
__global__ __launch_bounds__(256) void scan_blocks_kernel(
    const int* __restrict__ cnt, int n, int* __restrict__ off, int* __restrict__ part)
{
    __shared__ int lds[256];
    int tid = threadIdx.x;
    int base = blockIdx.x * 2048 + tid * 8;
    int v[8]; int s = 0;
    #pragma unroll
    for (int j = 0; j < 8; ++j){
        int idx = base + j;
        int c = (idx < n) ? cnt[idx] : 0;
        v[j] = s; s += c;
    }
    lds[tid] = s;
    __syncthreads();
    for (int d = 1; d < 256; d <<= 1){
        int t = (tid >= d) ? lds[tid - d] : 0;
        __syncthreads();
        lds[tid] += t;
        __syncthreads();
    }
    int thrBase = (tid > 0) ? lds[tid - 1] : 0;
    if (tid == 255) part[blockIdx.x] = lds[255];
    #pragma unroll
    for (int j = 0; j < 8; ++j){
        int idx = base + j;
        if (idx < n) off[idx] = thrBase + v[j];
    }
}

__global__ __launch_bounds__(128) void scan_part_kernel(
    int* __restrict__ part, int np, int* __restrict__ total_slot)
{
    __shared__ int lds[128];
    int tid = threadIdx.x;
    lds[tid] = (tid < np) ? part[tid] : 0;
    __syncthreads();
    for (int d = 1; d < 128; d <<= 1){
        int t = (tid >= d) ? lds[tid - d] : 0;
        __syncthreads();
        lds[tid] += t;
        __syncthreads();
    }
    if (tid < np) part[tid] = (tid > 0) ? lds[tid - 1] : 0;
    if (tid == 0) *total_slot = lds[np - 1 < 0 ? 0 : np - 1];
}

__global__ __launch_bounds__(256) void scan_add_kernel(
    int* __restrict__ off, const int* __restrict__ part, int n)
{
    int i = blockIdx.x * 256 + threadIdx.x;
    if (i < n) off[i] += part[i >> 11];
}

// ===== atomic-free fill: p = off[dst] + precomputed rank =====
__global__ __launch_bounds__(256) void fill3_kernel(
    const int* __restrict__ s0, const int* __restrict__ s1, const int* __restrict__ s2,
    const int* __restrict__ d0, const int* __restrict__ d1, const int* __restrict__ d2,
    const int* __restrict__ rk0, const int* __restrict__ rk1, const int* __restrict__ rk2,
    int E0, int E1, int E2, int b0, int b1, int b2, int n0, int n1, int n2,
    const int* __restrict__ off, int* __restrict__ slot)
{
    int t = blockIdx.y;
    int i = blockIdx.x * 256 + threadIdx.x;
    const int* sp = t == 0 ? s0 : (t == 1 ? s1 : s2);
    const int* dp = t == 0 ? d0 : (t == 1 ? d1 : d2);
    const int* rk = t == 0 ? rk0 : (t == 1 ? rk1 : rk2);
    int E = t == 0 ? E0 : (t == 1 ? E1 : E2);
    int b = t == 0 ? b0 : (t == 1 ? b1 : b2);
    int n = t == 0 ? n0 : (t == 1 ? n1 : n2);
    if (i < E){
        int x = dp[i];
        if ((unsigned)x < (unsigned)n){
            slot[off[b + x] + rk[i]] = sp[i];
        }
    }
}

// ===== fused gather + SAGE (NT edge types) + residual + LayerNorm =====
// NT=2: dst-type M (mm + hm aggregations, conv = 0.5*(o1n+o2n))
// NT=1: dst-type H (mh only, conv = o1n)
// Writes FINAL LayerNorm output directly; no conv buffer, no ln pass.
template<int NT>
__global__ __launch_bounds__(256) void sage_ln_kernel(
    const u16* __restrict__ Ts1, const u16* __restrict__ Ts2,
    const u16* __restrict__ Tdst,
    const int* __restrict__ off1, const int* __restrict__ off2,
    const int* __restrict__ slot, int ns1, int ns2,
    const float* __restrict__ Wl1, const float* __restrict__ bl1, const float* __restrict__ Wr1,
    const float* __restrict__ Wl2, const float* __restrict__ bl2, const float* __restrict__ Wr2,
    const float* __restrict__ g, const float* __restrict__ be,
    float* __restrict__ outp, int N, float scale)
{
    __shared__ u32 aggLDS[NT][16 * 68];
    __shared__ float redN[NT][4][16];   // per-edge-type sum-of-squares partials
    __shared__ float redS[2][4][16];    // LN sum / sumsq partials

    int tid = threadIdx.x;
    int wave = tid >> 6, lane = tid & 63;
    int ln16 = lane & 15, quad = lane >> 4;

    const u16* Ts[2] = {Ts1, Ts2};
    const int* offp[2] = {off1, off2};
    int nsv[2] = {ns1, ns2};
    const float* Wls[2] = {Wl1, Wl2};
    const float* Wrs[2] = {Wr1, Wr2};
    const float* bls[2] = {bl1, bl2};

    bf16x8 BL[NT][2][4], BR[NT][2][4];
    float bv[NT][2];
    #pragma unroll
    for (int et = 0; et < NT; ++et){
        #pragma unroll
        for (int t = 0; t < 2; ++t){
            int col = wave * 32 + t * 16 + ln16;
            #pragma unroll
            for (int q = 0; q < 4; ++q){
                bf16x8 fl, fr;
                #pragma unroll
                for (int j = 0; j < 8; ++j){
                    int k = q * 32 + quad * 8 + j;
                    fl[j] = (short)f2bf(Wls[et][k * 128 + col]);
                    fr[j] = (short)f2bf(Wrs[et][k * 128 + col]);
                }
                BL[et][t][q] = fl; BR[et][t][q] = fr;
            }
            bv[et][t] = bls[et][col];
        }
    }
    float gv[2], bev[2];
    #pragma unroll
    for (int t = 0; t < 2; ++t){
        int col = wave * 32 + t * 16 + ln16;
        gv[t] = g[col]; bev[t] = be[col];
    }

    int tiles = (N + 15) >> 4;
    for (int tile = blockIdx.x; tile < tiles; tile += gridDim.x){
        int row0 = tile * 16;

        // ---- phase 1: per edge type, lane-parallel slot prefetch + gather-mean ----
        #pragma unroll
        for (int et = 0; et < NT; ++et){
            const u16* Tsrc = Ts[et];
            const int* off = offp[et];
            int n_src = nsv[et];

            int rb[4], rdeg[4], rtake[4], myslot[4];
            #pragma unroll
            for (int r = 0; r < 4; ++r){
                int gg = row0 + wave * 4 + r;
                int b = 0, e = 0;
                if (gg < N){ b = off[gg]; e = off[gg + 1]; }
                rb[r] = b;
                int deg = e - b;
                rdeg[r] = deg;
                int take = deg < 64 ? deg : 64;
                rtake[r] = take;
                int s = 0;
                if (lane < take){
                    s = slot[b + lane];
                    if ((unsigned)s >= (unsigned)n_src) s = 0;
                }
                myslot[r] = s;
            }

            #pragma unroll
            for (int r = 0; r < 4; ++r){
                int lrow = wave * 4 + r;
                float p0 = 0.f, p1 = 0.f, q0 = 0.f, q1 = 0.f;
                float r0 = 0.f, r1 = 0.f, s0 = 0.f, s1 = 0.f;
                int take = rtake[r];
                int j = 0;
                for (; j + 4 <= take; j += 4){
                    int i0 = __shfl(myslot[r], j);
                    int i1 = __shfl(myslot[r], j + 1);
                    int i2 = __shfl(myslot[r], j + 2);
                    int i3 = __shfl(myslot[r], j + 3);
                    u32 u0 = *(const u32*)(Tsrc + (size_t)i0 * 128 + lane * 2);
                    u32 u1 = *(const u32*)(Tsrc + (size_t)i1 * 128 + lane * 2);
                    u32 u2 = *(const u32*)(Tsrc + (size_t)i2 * 128 + lane * 2);
                    u32 u3 = *(const u32*)(Tsrc + (size_t)i3 * 128 + lane * 2);
                    p0 += bf_lo(u0); p1 += bf_hi(u0);
                    q0 += bf_lo(u1); q1 += bf_hi(u1);
                    r0 += bf_lo(u2); r1 += bf_hi(u2);
                    s0 += bf_lo(u3); s1 += bf_hi(u3);
                }
                for (; j < take; ++j){
                    int i0 = __shfl(myslot[r], j);
                    u32 u0 = *(const u32*)(Tsrc + (size_t)i0 * 128 + lane * 2);
                    p0 += bf_lo(u0); p1 += bf_hi(u0);
                }
                for (int j2 = rb[r] + 64; j2 < rb[r] + rdeg[r]; ++j2){
                    int i0 = slot[j2];
                    if ((unsigned)i0 >= (unsigned)n_src) i0 = 0;
                    u32 u0 = *(const u32*)(Tsrc + (size_t)i0 * 128 + lane * 2);
                    p0 += bf_lo(u0); p1 += bf_hi(u0);
                }
                float a0 = (p0 + q0) + (r0 + s0);
                float a1 = (p1 + q1) + (r1 + s1);
                int c = rdeg[r] < 1 ? 1 : rdeg[r];
                float inv = 1.0f / (float)c;
                aggLDS[et][lrow * 68 + lane] = pack2(a0 * inv, a1 * inv);
            }
        }
        __syncthreads();

        // ---- phase 2: GEMMs on [agg_et | Tdst], shared Tdst A-fragment ----
        int ar = row0 + ln16; if (ar > N - 1) ar = N - 1;
        const u16* Ar2 = Tdst + (size_t)ar * 128 + quad * 8;
        f32x4 acc[NT][2];
        #pragma unroll
        for (int et = 0; et < NT; ++et)
            #pragma unroll
            for (int t = 0; t < 2; ++t)
                acc[et][t] = (f32x4){bv[et][t], bv[et][t], bv[et][t], bv[et][t]};
        #pragma unroll
        for (int q = 0; q < 4; ++q){
            bf16x8 afr = *(const bf16x8*)(Ar2 + q * 32);
            #pragma unroll
            for (int et = 0; et < NT; ++et){
                bf16x8 afl = *(const bf16x8*)&aggLDS[et][ln16 * 68 + q * 16 + quad * 4];
                #pragma unroll
                for (int t = 0; t < 2; ++t){
                    acc[et][t] = __builtin_amdgcn_mfma_f32_16x16x32_bf16(afl, BL[et][t][q], acc[et][t], 0, 0, 0);
                    acc[et][t] = __builtin_amdgcn_mfma_f32_16x16x32_bf16(afr, BR[et][t][q], acc[et][t], 0, 0, 0);
                }
            }
        }

        // ---- phase 3a: per-edge-type row sum-of-squares (cross-wave) ----
        #pragma unroll
        for (int et = 0; et < NT; ++et){
            #pragma unroll
            for (int r = 0; r < 4; ++r){
                float s = acc[et][0][r] * acc[et][0][r] + acc[et][1][r] * acc[et][1][r];
                #pragma unroll
                for (int m = 1; m < 16; m <<= 1) s += __shfl_xor(s, m);
                if (ln16 == 0) redN[et][wave][quad * 4 + r] = s;
            }
        }
        __syncthreads();

        // ---- phase 3b: norm-scale, residual add, LN partial sums ----
        float yv[2][4];
        float lsum[4], lsq[4];
        #pragma unroll
        for (int r = 0; r < 4; ++r){
            int r16 = quad * 4 + r;
            int row = row0 + r16;
            int crow = row < N ? row : N - 1;
            float sc[NT];
            #pragma unroll
            for (int et = 0; et < NT; ++et){
                float tot = redN[et][0][r16] + redN[et][1][r16] + redN[et][2][r16] + redN[et][3][r16];
                sc[et] = scale / fmaxf(sqrtf(tot), 1e-12f);
            }
            float s1v = 0.f, s2v = 0.f;
            #pragma unroll
            for (int t = 0; t < 2; ++t){
                int col = wave * 32 + t * 16 + ln16;
                float y = bf2f(Tdst[(size_t)crow * 128 + col]);
                #pragma unroll
                for (int et = 0; et < NT; ++et) y += acc[et][t][r] * sc[et];
                yv[t][r] = y;
                s1v += y; s2v += y * y;
            }
            #pragma unroll
            for (int m = 1; m < 16; m <<= 1){ s1v += __shfl_xor(s1v, m); s2v += __shfl_xor(s2v, m); }
            lsum[r] = s1v; lsq[r] = s2v;
        }
        if (ln16 == 0){
            #pragma unroll
            for (int r = 0; r < 4; ++r){
                redS[0][wave][quad * 4 + r] = lsum[r];
                redS[1][wave][quad * 4 + r] = lsq[r];
            }
        }
        __syncthreads();

        // ---- phase 3c: final LayerNorm write ----
        #pragma unroll
        for (int r = 0; r < 4; ++r){
            int r16 = quad * 4 + r;
            int row = row0 + r16;
            if (row >= N) continue;
            float S1 = redS[0][0][r16] + redS[0][1][r16] + redS[0][2][r16] + redS[0][3][r16];
            float S2 = redS[1][0][r16] + redS[1][1][r16] + redS[1][2][r16] + redS[1][3][r16];
            float mean = S1 * (1.0f / 128.0f);
            float var = S2 * (1.0f / 128.0f) - mean * mean;
            float rstd = rsqrtf(var + 1e-5f);
            #pragma unroll
            for (int t = 0; t < 2; ++t){
                int col = wave * 32 + t * 16 + ln16;
                outp[(size_t)row * 128 + col] = (yv[t][r] - mean) * rstd * gv[t] + bev[t];
            }
        }
        __syncthreads();
    }
}

extern "C" void kernel_launch(void* const* d_in, const int* in_sizes, int n_in,
                              void* d_out, int out_size, void* d_ws, size_t ws_size,
                              hipStream_t stream) {
    const float* xm    = (const float*)d_in[0];
    const float* xh    = (const float*)d_in[1];
    const float* Wnt_m = (const float*)d_in[2];  const float* bnt_m = (const float*)d_in[3];
    const float* Wnt_h = (const float*)d_in[4];  const float* bnt_h = (const float*)d_in[5];
    const float* Wl_mm = (const float*)d_in[6];  const float* bl_mm = (const float*)d_in[7];
    const float* Wr_mm = (const float*)d_in[8];
    const float* Wl_mh = (const float*)d_in[9];  const float* bl_mh = (const float*)d_in[10];
    const float* Wr_mh = (const float*)d_in[11];
    const float* Wl_hm = (const float*)d_in[12]; const float* bl_hm = (const float*)d_in[13];
    const float* Wr_hm = (const float*)d_in[14];
    const float* g_m   = (const float*)d_in[15]; const float* be_m  = (const float*)d_in[16];
    const float* g_h   = (const float*)d_in[17]; const float* be_h  = (const float*)d_in[18];
    const int* ei_mm = (const int*)d_in[19];
    const int* ei_mh = (const int*)d_in[20];
    const int* ei_hm = (const int*)d_in[21];

    const int D = 128;
    const int NM = in_sizes[0] / D;
    const int NH = in_sizes[1] / D;
    const int E1 = in_sizes[19] / 2;   // mm
    const int E2 = in_sizes[20] / 2;   // mh
    const int E3 = in_sizes[21] / 2;   // hm
    const int Esum = E1 + E2 + E3;
    const int n3 = 2 * NM + NH;        // type0: mm->M, type1: hm->M, type2: mh->H

    char* ws = (char*)d_ws;
    size_t woff = 0;
    auto alloc = [&](size_t bytes) -> void* {
        void* p = ws + woff;
        woff += (bytes + 255) & ~(size_t)255;
        return p;
    };
    u16* T_M   = (u16*)alloc((size_t)NM * D * 2);
    u16* T_H   = (u16*)alloc((size_t)NH * D * 2);
    int* CNT3  = (int*)alloc((size_t)n3 * 4);
    int* OFF3  = (int*)alloc((size_t)(n3 + 1) * 4);
    int* SLOT3 = (int*)alloc((size_t)Esum * 4);
    int* PART  = (int*)alloc(1024 * 4);
    if (woff > ws_size) return;

    // rank scratch lives in d_out: fully consumed by fill3 before any out write
    int* RANK3 = (int*)d_out;
    int* rk0 = RANK3, *rk1 = RANK3 + E1, *rk2 = RANK3 + E1 + E3;

    float* OUT_M = (float*)d_out;
    float* OUT_H = (float*)d_out + (size_t)NM * D;

    const int b0 = 0, b1 = NM, b2 = 2 * NM;
    const int h0 = (E1 + 255) / 256, h1 = (E3 + 255) / 256, h2 = (E2 + 255) / 256;
    const int gm = 1024, gh = 1024;
    int Emax = E1 > E2 ? E1 : E2; if (E3 > Emax) Emax = E3;
    const dim3 egrid((Emax + 255) / 256, 3);
    const int scanBlocks = (n3 + 2047) / 2048;

    hipMemsetAsync(CNT3, 0, (size_t)n3 * 4, stream);

    fusedA_kernel<<<h0 + h1 + h2 + gm + gh, 256, 0, stream>>>(
        ei_mm + E1, ei_hm + E3, ei_mh + E2,
        rk0, rk1, rk2,
        E1, E3, E2, b0, b1, b2, NM, NM, NH, CNT3, h0, h1, h2,
        xm, Wnt_m, bnt_m, T_M, NM,
        xh, Wnt_h, bnt_h, T_H, NH, gm, gh);

    scan_blocks_kernel<<<scanBlocks, 256, 0, stream>>>(CNT3, n3, OFF3, PART);
    scan_part_kernel<<<1, 128, 0, stream>>>(PART, scanBlocks, OFF3 + n3);
    scan_add_kernel<<<(n3 + 255) / 256, 256, 0, stream>>>(OFF3, PART, n3);
    fill3_kernel<<<egrid, 256, 0, stream>>>(
        ei_mm, ei_hm, ei_mh,
        ei_mm + E1, ei_hm + E3, ei_mh + E2,
        rk0, rk1, rk2,
        E1, E3, E2, b0, b1, b2, NM, NM, NH, OFF3, SLOT3);

    // M nodes: mm + hm edge types, conv = 0.5*(o_mm + o_hm), fused residual+LN
    sage_ln_kernel<2><<<(NM + 15) / 16, 256, 0, stream>>>(
        T_M, T_H, T_M, OFF3 + b0, OFF3 + b1, SLOT3, NM, NH,
        Wl_mm, bl_mm, Wr_mm, Wl_hm, bl_hm, Wr_hm,
        g_m, be_m, OUT_M, NM, 0.5f);
    // H nodes: mh edge type only, fused residual+LN
    sage_ln_kernel<1><<<(NH + 15) / 16, 256, 0, stream>>>(
        T_M, nullptr, T_H, OFF3 + b2, nullptr, SLOT3, NM, 0,
        Wl_mh, bl_mh, Wr_mh, nullptr, nullptr, nullptr,
        g_h, be_h, OUT_H, NH, 1.0f);
}

// Round 2
// 540.964 us; speedup vs baseline: 1.1677x; 1.0245x over previous
//
#include <hip/hip_runtime.h>

typedef unsigned short u16;
typedef unsigned int u32;
typedef __attribute__((ext_vector_type(8))) short bf16x8;
typedef __attribute__((ext_vector_type(4))) float f32x4;

__device__ __forceinline__ float bf_lo(u32 u){ return __uint_as_float(u << 16); }
__device__ __forceinline__ float bf_hi(u32 u){ return __uint_as_float(u & 0xffff0000u); }
__device__ __forceinline__ float bf2f(u16 v){ return __uint_as_float((u32)v << 16); }
__device__ __forceinline__ u16 f2bf(float f){
    u32 u = __float_as_uint(f);
    u32 r = (u + 0x7fffu + ((u >> 16) & 1u)) >> 16;
    return (u16)r;
}
__device__ __forceinline__ u32 pack2(float a, float b){
    return (u32)f2bf(a) | ((u32)f2bf(b) << 16);
}

// ======== fused: hist3+rank || weight-fragment pre-swizzle || ntgemm_M || ntgemm_H ========
// Weight fragment layout (per 128x128 matrix, 16384 bf16):
//   idx(w,t,q,quad,ln16,j) = ((((w*2+t)*4+q)*4+quad)*16+ln16)*8 + j
//   element = W[(q*32+quad*8+j)*128 + (w*32+t*16+ln16)]
__global__ __launch_bounds__(256) void fusedA_kernel(
    const int* __restrict__ d0, const int* __restrict__ d1, const int* __restrict__ d2,
    int* __restrict__ rk0, int* __restrict__ rk1, int* __restrict__ rk2,
    int E0, int E1, int E2, int b0, int b1, int b2, int n0, int n1, int n2,
    int* __restrict__ cnt, int h0, int h1, int h2,
    const float* __restrict__ Wf0, const float* __restrict__ Wf1,
    const float* __restrict__ Wf2, const float* __restrict__ Wf3,
    const float* __restrict__ Wf4, const float* __restrict__ Wf5,
    u16* __restrict__ WF,
    const float* __restrict__ Xm, const float* __restrict__ Wm,
    const float* __restrict__ bm, u16* __restrict__ Tm, int NM,
    const float* __restrict__ Xh, const float* __restrict__ Wh,
    const float* __restrict__ bh, u16* __restrict__ Th, int NH,
    int gm, int gh)
{
    int bid = blockIdx.x;
    int HB = h0 + h1 + h2;
    if (bid < HB){
        int t, lb;
        if (bid < h0){ t = 0; lb = bid; }
        else if (bid < h0 + h1){ t = 1; lb = bid - h0; }
        else { t = 2; lb = bid - h0 - h1; }
        const int* d = t == 0 ? d0 : (t == 1 ? d1 : d2);
        int* rk = t == 0 ? rk0 : (t == 1 ? rk1 : rk2);
        int E = t == 0 ? E0 : (t == 1 ? E1 : E2);
        int b = t == 0 ? b0 : (t == 1 ? b1 : b2);
        int n = t == 0 ? n0 : (t == 1 ? n1 : n2);
        int i = lb * 256 + threadIdx.x;
        if (i < E){
            int x = d[i];
            if ((unsigned)x < (unsigned)n) rk[i] = atomicAdd(&cnt[b + x], 1);
        }
        return;
    }
    bid -= HB;
    if (bid < 6){
        const float* W = bid == 0 ? Wf0 : bid == 1 ? Wf1 : bid == 2 ? Wf2 :
                         bid == 3 ? Wf3 : bid == 4 ? Wf4 : Wf5;
        u16* dst = WF + (size_t)bid * 16384;
        #pragma unroll 4
        for (int k = 0; k < 64; ++k){
            int i = k * 256 + threadIdx.x;
            int j   = i & 7;
            int l16 = (i >> 3) & 15;
            int qd  = (i >> 7) & 3;
            int q   = (i >> 9) & 3;
            int tt  = (i >> 11) & 1;
            int w   = (i >> 12) & 3;
            dst[i] = f2bf(W[(q * 32 + qd * 8 + j) * 128 + (w * 32 + tt * 16 + l16)]);
        }
        return;
    }
    bid -= 6;
    const float *A, *W, *bias; u16* C; int N, lgrid, lbid;
    if (bid < gm){ A = Xm; W = Wm; bias = bm; C = Tm; N = NM; lgrid = gm; lbid = bid; }
    else         { A = Xh; W = Wh; bias = bh; C = Th; N = NH; lgrid = gh; lbid = bid - gm; }

    int tid = threadIdx.x;
    int wave = tid >> 6, lane = tid & 63;
    int colHalf = wave & 1;
    int ln16 = lane & 15, quad = lane >> 4;

    bf16x8 Bfrag[4][4];
    #pragma unroll
    for (int t = 0; t < 4; ++t){
        int col = colHalf * 64 + t * 16 + ln16;
        #pragma unroll
        for (int q = 0; q < 4; ++q){
            bf16x8 f;
            #pragma unroll
            for (int j = 0; j < 8; ++j)
                f[j] = (short)f2bf(W[(q * 32 + quad * 8 + j) * 128 + col]);
            Bfrag[t][q] = f;
        }
    }
    float bv[4];
    #pragma unroll
    for (int t = 0; t < 4; ++t)
        bv[t] = bias[colHalf * 64 + t * 16 + ln16];

    int rowBlocks = (N + 15) >> 4;
    for (int rb = lbid * 2 + (wave >> 1); rb < rowBlocks; rb += lgrid * 2){
        int row0 = rb * 16;
        int ar = row0 + ln16; if (ar > N - 1) ar = N - 1;
        const float* Arow = A + (size_t)ar * 128 + quad * 8;
        bf16x8 Af[4];
        #pragma unroll
        for (int q = 0; q < 4; ++q){
            f32x4 lo = *(const f32x4*)(Arow + q * 32);
            f32x4 hi = *(const f32x4*)(Arow + q * 32 + 4);
            bf16x8 f;
            #pragma unroll
            for (int j = 0; j < 4; ++j){ f[j] = (short)f2bf(lo[j]); f[4+j] = (short)f2bf(hi[j]); }
            Af[q] = f;
        }
        f32x4 acc[4];
        #pragma unroll
        for (int t = 0; t < 4; ++t) acc[t] = (f32x4){bv[t], bv[t], bv[t], bv[t]};
        #pragma unroll
        for (int q = 0; q < 4; ++q)
            #pragma unroll
            for (int t = 0; t < 4; ++t)
                acc[t] = __builtin_amdgcn_mfma_f32_16x16x32_bf16(Af[q], Bfrag[t][q], acc[t], 0, 0, 0);
        #pragma unroll
        for (int t = 0; t < 4; ++t){
            int col = colHalf * 64 + t * 16 + ln16;
            #pragma unroll
            for (int r = 0; r < 4; ++r){
                int row = row0 + quad * 4 + r;
                if (row < N) C[(size_t)row * 128 + col] = f2bf(acc[t][r]);
            }
        }
    }
}

// ---------------- 3-phase device-wide exclusive scan ----------------
__global__ __launch_bounds__(256) void scan_blocks_kernel(
    const int* __restrict__ cnt, int n, int* __restrict__ off, int* __restrict__ part)
{
    __shared__ int lds[256];
    int tid = threadIdx.x;
    int base = blockIdx.x * 2048 + tid * 8;
    int v[8]; int s = 0;
    #pragma unroll
    for (int j = 0; j < 8; ++j){
        int idx = base + j;
        int c = (idx < n) ? cnt[idx] : 0;
        v[j] = s; s += c;
    }
    lds[tid] = s;
    __syncthreads();
    for (int d = 1; d < 256; d <<= 1){
        int t = (tid >= d) ? lds[tid - d] : 0;
        __syncthreads();
        lds[tid] += t;
        __syncthreads();
    }
    int thrBase = (tid > 0) ? lds[tid - 1] : 0;
    if (tid == 255) part[blockIdx.x] = lds[255];
    #pragma unroll
    for (int j = 0; j < 8; ++j){
        int idx = base + j;
        if (idx < n) off[idx] = thrBase + v[j];
    }
}

__global__ __launch_bounds__(128) void scan_part_kernel(
    int* __restrict__ part, int np, int* __restrict__ total_slot)
{
    __shared__ int lds[128];
    int tid = threadIdx.x;
    lds[tid] = (tid < np) ? part[tid] : 0;
    __syncthreads();
    for (int d = 1; d < 128; d <<= 1){
        int t = (tid >= d) ? lds[tid - d] : 0;
        __syncthreads();
        lds[tid] += t;
        __syncthreads();
    }
    if (tid < np) part[tid] = (tid > 0) ? lds[tid - 1] : 0;
    if (tid == 0) *total_slot = lds[np - 1 < 0 ? 0 : np - 1];
}

__global__ __launch_bounds__(256) void scan_add_kernel(
    int* __restrict__ off, const int* __restrict__ part, int n)
{
    int i = blockIdx.x * 256 + threadIdx.x;
    if (i < n) off[i] += part[i >> 11];
}

// ===== atomic-free fill: p = off[dst] + precomputed rank =====
__global__ __launch_bounds__(256) void fill3_kernel(
    const int* __restrict__ s0, const int* __restrict__ s1, const int* __restrict__ s2,
    const int* __restrict__ d0, const int* __restrict__ d1, const int* __restrict__ d2,
    const int* __restrict__ rk0, const int* __restrict__ rk1, const int* __restrict__ rk2,
    int E0, int E1, int E2, int b0, int b1, int b2, int n0, int n1, int n2,
    const int* __restrict__ off, int* __restrict__ slot)
{
    int t = blockIdx.y;
    int i = blockIdx.x * 256 + threadIdx.x;
    const int* sp = t == 0 ? s0 : (t == 1 ? s1 : s2);
    const int* dp = t == 0 ? d0 : (t == 1 ? d1 : d2);
    const int* rk = t == 0 ? rk0 : (t == 1 ? rk1 : rk2);
    int E = t == 0 ? E0 : (t == 1 ? E1 : E2);
    int b = t == 0 ? b0 : (t == 1 ? b1 : b2);
    int n = t == 0 ? n0 : (t == 1 ? n1 : n2);
    if (i < E){
        int x = dp[i];
        if ((unsigned)x < (unsigned)n){
            slot[off[b + x] + rk[i]] = sp[i];
        }
    }
}

// ===== fused gather + SAGE (NT edge types) + residual + LayerNorm =====
// Weights come pre-swizzled (bf16, fragment order) so phase 1 carries no
// weight registers; fragments are loaded as 16B vectors inside phase 2.
template<int NT>
__global__ __launch_bounds__(256, 4) void sage_ln_kernel(
    const u16* __restrict__ Ts1, const u16* __restrict__ Ts2,
    const u16* __restrict__ Tdst,
    const int* __restrict__ off1, const int* __restrict__ off2,
    const int* __restrict__ slot, int ns1, int ns2,
    const u16* __restrict__ WFl1, const u16* __restrict__ WFr1, const float* __restrict__ bl1,
    const u16* __restrict__ WFl2, const u16* __restrict__ WFr2, const float* __restrict__ bl2,
    const float* __restrict__ g, const float* __restrict__ be,
    float* __restrict__ outp, int N, float scale)
{
    __shared__ u32 aggLDS[NT][16 * 68];
    __shared__ float redN[NT][4][16];   // per-edge-type sum-of-squares partials
    __shared__ float redS[2][4][16];    // LN sum / sumsq partials

    int tid = threadIdx.x;
    int wave = tid >> 6, lane = tid & 63;
    int ln16 = lane & 15, quad = lane >> 4;

    const u16* Ts[2] = {Ts1, Ts2};
    const int* offp[2] = {off1, off2};
    int nsv[2] = {ns1, ns2};
    const u16* WFl[2] = {WFl1, WFl2};
    const u16* WFr[2] = {WFr1, WFr2};
    const float* bls[2] = {bl1, bl2};

    float bv[NT][2];
    #pragma unroll
    for (int et = 0; et < NT; ++et)
        #pragma unroll
        for (int t = 0; t < 2; ++t)
            bv[et][t] = bls[et][wave * 32 + t * 16 + ln16];
    float gv[2], bev[2];
    #pragma unroll
    for (int t = 0; t < 2; ++t){
        int col = wave * 32 + t * 16 + ln16;
        gv[t] = g[col]; bev[t] = be[col];
    }

    int tiles = (N + 15) >> 4;
    for (int tile = blockIdx.x; tile < tiles; tile += gridDim.x){
        int row0 = tile * 16;

        // ---- phase 1: per edge type, lane-parallel slot prefetch + gather-mean ----
        #pragma unroll
        for (int et = 0; et < NT; ++et){
            const u16* Tsrc = Ts[et];
            const int* off = offp[et];
            int n_src = nsv[et];

            int rb[4], rdeg[4], rtake[4], myslot[4];
            #pragma unroll
            for (int r = 0; r < 4; ++r){
                int gg = row0 + wave * 4 + r;
                int b = 0, e = 0;
                if (gg < N){ b = off[gg]; e = off[gg + 1]; }
                rb[r] = b;
                int deg = e - b;
                rdeg[r] = deg;
                int take = deg < 64 ? deg : 64;
                rtake[r] = take;
                int s = 0;
                if (lane < take){
                    s = slot[b + lane];
                    if ((unsigned)s >= (unsigned)n_src) s = 0;
                }
                myslot[r] = s;
            }

            #pragma unroll
            for (int r = 0; r < 4; ++r){
                int lrow = wave * 4 + r;
                float p0 = 0.f, p1 = 0.f, q0 = 0.f, q1 = 0.f;
                float r0 = 0.f, r1 = 0.f, s0 = 0.f, s1 = 0.f;
                int take = rtake[r];
                int j = 0;
                for (; j + 4 <= take; j += 4){
                    int i0 = __shfl(myslot[r], j);
                    int i1 = __shfl(myslot[r], j + 1);
                    int i2 = __shfl(myslot[r], j + 2);
                    int i3 = __shfl(myslot[r], j + 3);
                    u32 u0 = *(const u32*)(Tsrc + (size_t)i0 * 128 + lane * 2);
                    u32 u1 = *(const u32*)(Tsrc + (size_t)i1 * 128 + lane * 2);
                    u32 u2 = *(const u32*)(Tsrc + (size_t)i2 * 128 + lane * 2);
                    u32 u3 = *(const u32*)(Tsrc + (size_t)i3 * 128 + lane * 2);
                    p0 += bf_lo(u0); p1 += bf_hi(u0);
                    q0 += bf_lo(u1); q1 += bf_hi(u1);
                    r0 += bf_lo(u2); r1 += bf_hi(u2);
                    s0 += bf_lo(u3); s1 += bf_hi(u3);
                }
                for (; j < take; ++j){
                    int i0 = __shfl(myslot[r], j);
                    u32 u0 = *(const u32*)(Tsrc + (size_t)i0 * 128 + lane * 2);
                    p0 += bf_lo(u0); p1 += bf_hi(u0);
                }
                for (int j2 = rb[r] + 64; j2 < rb[r] + rdeg[r]; ++j2){
                    int i0 = slot[j2];
                    if ((unsigned)i0 >= (unsigned)n_src) i0 = 0;
                    u32 u0 = *(const u32*)(Tsrc + (size_t)i0 * 128 + lane * 2);
                    p0 += bf_lo(u0); p1 += bf_hi(u0);
                }
                float a0 = (p0 + q0) + (r0 + s0);
                float a1 = (p1 + q1) + (r1 + s1);
                int c = rdeg[r] < 1 ? 1 : rdeg[r];
                float inv = 1.0f / (float)c;
                aggLDS[et][lrow * 68 + lane] = pack2(a0 * inv, a1 * inv);
            }
        }
        __syncthreads();

        // ---- phase 2: GEMMs on [agg_et | Tdst]; weight frags streamed from L2 ----
        int ar = row0 + ln16; if (ar > N - 1) ar = N - 1;
        const u16* Ar2 = Tdst + (size_t)ar * 128 + quad * 8;
        f32x4 acc[NT][2];
        #pragma unroll
        for (int et = 0; et < NT; ++et)
            #pragma unroll
            for (int t = 0; t < 2; ++t)
                acc[et][t] = (f32x4){bv[et][t], bv[et][t], bv[et][t], bv[et][t]};
        #pragma unroll
        for (int q = 0; q < 4; ++q){
            bf16x8 afr = *(const bf16x8*)(Ar2 + q * 32);
            #pragma unroll
            for (int et = 0; et < NT; ++et){
                bf16x8 afl = *(const bf16x8*)&aggLDS[et][ln16 * 68 + q * 16 + quad * 4];
                #pragma unroll
                for (int t = 0; t < 2; ++t){
                    int fo = ((((wave * 2 + t) * 4 + q) * 4 + quad) * 16 + ln16) * 8;
                    bf16x8 BLf = *(const bf16x8*)(WFl[et] + fo);
                    bf16x8 BRf = *(const bf16x8*)(WFr[et] + fo);
                    acc[et][t] = __builtin_amdgcn_mfma_f32_16x16x32_bf16(afl, BLf, acc[et][t], 0, 0, 0);
                    acc[et][t] = __builtin_amdgcn_mfma_f32_16x16x32_bf16(afr, BRf, acc[et][t], 0, 0, 0);
                }
            }
        }

        // ---- phase 3a: per-edge-type row sum-of-squares (cross-wave) ----
        #pragma unroll
        for (int et = 0; et < NT; ++et){
            #pragma unroll
            for (int r = 0; r < 4; ++r){
                float s = acc[et][0][r] * acc[et][0][r] + acc[et][1][r] * acc[et][1][r];
                #pragma unroll
                for (int m = 1; m < 16; m <<= 1) s += __shfl_xor(s, m);
                if (ln16 == 0) redN[et][wave][quad * 4 + r] = s;
            }
        }
        __syncthreads();

        // ---- phase 3b: norm-scale, residual add, LN partial sums ----
        float yv[2][4];
        float lsum[4], lsq[4];
        #pragma unroll
        for (int r = 0; r < 4; ++r){
            int r16 = quad * 4 + r;
            int row = row0 + r16;
            int crow = row < N ? row : N - 1;
            float sc[NT];
            #pragma unroll
            for (int et = 0; et < NT; ++et){
                float tot = redN[et][0][r16] + redN[et][1][r16] + redN[et][2][r16] + redN[et][3][r16];
                sc[et] = scale / fmaxf(sqrtf(tot), 1e-12f);
            }
            float s1v = 0.f, s2v = 0.f;
            #pragma unroll
            for (int t = 0; t < 2; ++t){
                int col = wave * 32 + t * 16 + ln16;
                float y = bf2f(Tdst[(size_t)crow * 128 + col]);
                #pragma unroll
                for (int et = 0; et < NT; ++et) y += acc[et][t][r] * sc[et];
                yv[t][r] = y;
                s1v += y; s2v += y * y;
            }
            #pragma unroll
            for (int m = 1; m < 16; m <<= 1){ s1v += __shfl_xor(s1v, m); s2v += __shfl_xor(s2v, m); }
            lsum[r] = s1v; lsq[r] = s2v;
        }
        if (ln16 == 0){
            #pragma unroll
            for (int r = 0; r < 4; ++r){
                redS[0][wave][quad * 4 + r] = lsum[r];
                redS[1][wave][quad * 4 + r] = lsq[r];
            }
        }
        __syncthreads();

        // ---- phase 3c: final LayerNorm write ----
        #pragma unroll
        for (int r = 0; r < 4; ++r){
            int r16 = quad * 4 + r;
            int row = row0 + r16;
            if (row >= N) continue;
            float S1 = redS[0][0][r16] + redS[0][1][r16] + redS[0][2][r16] + redS[0][3][r16];
            float S2 = redS[1][0][r16] + redS[1][1][r16] + redS[1][2][r16] + redS[1][3][r16];
            float mean = S1 * (1.0f / 128.0f);
            float var = S2 * (1.0f / 128.0f) - mean * mean;
            float rstd = rsqrtf(var + 1e-5f);
            #pragma unroll
            for (int t = 0; t < 2; ++t){
                int col = wave * 32 + t * 16 + ln16;
                outp[(size_t)row * 128 + col] = (yv[t][r] - mean) * rstd * gv[t] + bev[t];
            }
        }
        __syncthreads();
    }
}

extern "C" void kernel_launch(void* const* d_in, const int* in_sizes, int n_in,
                              void* d_out, int out_size, void* d_ws, size_t ws_size,
                              hipStream_t stream) {
    const float* xm    = (const float*)d_in[0];
    const float* xh    = (const float*)d_in[1];
    const float* Wnt_m = (const float*)d_in[2];  const float* bnt_m = (const float*)d_in[3];
    const float* Wnt_h = (const float*)d_in[4];  const float* bnt_h = (const float*)d_in[5];
    const float* Wl_mm = (const float*)d_in[6];  const float* bl_mm = (const float*)d_in[7];
    const float* Wr_mm = (const float*)d_in[8];
    const float* Wl_mh = (const float*)d_in[9];  const float* bl_mh = (const float*)d_in[10];
    const float* Wr_mh = (const float*)d_in[11];
    const float* Wl_hm = (const float*)d_in[12]; const float* bl_hm = (const float*)d_in[13];
    const float* Wr_hm = (const float*)d_in[14];
    const float* g_m   = (const float*)d_in[15]; const float* be_m  = (const float*)d_in[16];
    const float* g_h   = (const float*)d_in[17]; const float* be_h  = (const float*)d_in[18];
    const int* ei_mm = (const int*)d_in[19];
    const int* ei_mh = (const int*)d_in[20];
    const int* ei_hm = (const int*)d_in[21];

    const int D = 128;
    const int NM = in_sizes[0] / D;
    const int NH = in_sizes[1] / D;
    const int E1 = in_sizes[19] / 2;   // mm
    const int E2 = in_sizes[20] / 2;   // mh
    const int E3 = in_sizes[21] / 2;   // hm
    const int Esum = E1 + E2 + E3;
    const int n3 = 2 * NM + NH;        // type0: mm->M, type1: hm->M, type2: mh->H

    char* ws = (char*)d_ws;
    size_t woff = 0;
    auto alloc = [&](size_t bytes) -> void* {
        void* p = ws + woff;
        woff += (bytes + 255) & ~(size_t)255;
        return p;
    };
    u16* T_M   = (u16*)alloc((size_t)NM * D * 2);
    u16* T_H   = (u16*)alloc((size_t)NH * D * 2);
    int* CNT3  = (int*)alloc((size_t)n3 * 4);
    int* OFF3  = (int*)alloc((size_t)(n3 + 1) * 4);
    int* SLOT3 = (int*)alloc((size_t)Esum * 4);
    int* PART  = (int*)alloc(1024 * 4);
    u16* WF    = (u16*)alloc((size_t)6 * 16384 * 2);   // pre-swizzled bf16 weights
    if (woff > ws_size) return;

    // rank scratch lives in d_out: fully consumed by fill3 before any out write
    int* RANK3 = (int*)d_out;
    int* rk0 = RANK3, *rk1 = RANK3 + E1, *rk2 = RANK3 + E1 + E3;

    float* OUT_M = (float*)d_out;
    float* OUT_H = (float*)d_out + (size_t)NM * D;

    const int b0 = 0, b1 = NM, b2 = 2 * NM;
    const int h0 = (E1 + 255) / 256, h1 = (E3 + 255) / 256, h2 = (E2 + 255) / 256;
    const int gm = 1024, gh = 1024;
    int Emax = E1 > E2 ? E1 : E2; if (E3 > Emax) Emax = E3;
    const dim3 egrid((Emax + 255) / 256, 3);
    const int scanBlocks = (n3 + 2047) / 2048;

    hipMemsetAsync(CNT3, 0, (size_t)n3 * 4, stream);

    fusedA_kernel<<<h0 + h1 + h2 + 6 + gm + gh, 256, 0, stream>>>(
        ei_mm + E1, ei_hm + E3, ei_mh + E2,
        rk0, rk1, rk2,
        E1, E3, E2, b0, b1, b2, NM, NM, NH, CNT3, h0, h1, h2,
        Wl_mm, Wr_mm, Wl_hm, Wr_hm, Wl_mh, Wr_mh, WF,
        xm, Wnt_m, bnt_m, T_M, NM,
        xh, Wnt_h, bnt_h, T_H, NH, gm, gh);

    scan_blocks_kernel<<<scanBlocks, 256, 0, stream>>>(CNT3, n3, OFF3, PART);
    scan_part_kernel<<<1, 128, 0, stream>>>(PART, scanBlocks, OFF3 + n3);
    scan_add_kernel<<<(n3 + 255) / 256, 256, 0, stream>>>(OFF3, PART, n3);
    fill3_kernel<<<egrid, 256, 0, stream>>>(
        ei_mm, ei_hm, ei_mh,
        ei_mm + E1, ei_hm + E3, ei_mh + E2,
        rk0, rk1, rk2,
        E1, E3, E2, b0, b1, b2, NM, NM, NH, OFF3, SLOT3);

    // M nodes: mm + hm edge types, conv = 0.5*(o_mm + o_hm), fused residual+LN
    sage_ln_kernel<2><<<(NM + 15) / 16, 256, 0, stream>>>(
        T_M, T_H, T_M, OFF3 + b0, OFF3 + b1, SLOT3, NM, NH,
        WF + 0 * 16384, WF + 1 * 16384, bl_mm,
        WF + 2 * 16384, WF + 3 * 16384, bl_hm,
        g_m, be_m, OUT_M, NM, 0.5f);
    // H nodes: mh edge type only, fused residual+LN
    sage_ln_kernel<1><<<(NH + 15) / 16, 256, 0, stream>>>(
        T_M, nullptr, T_H, OFF3 + b2, nullptr, SLOT3, NM, 0,
        WF + 4 * 16384, WF + 5 * 16384, bl_mh,
        nullptr, nullptr, nullptr,
        g_h, be_h, OUT_H, NH, 1.0f);
}

// Round 3
// 442.383 us; speedup vs baseline: 1.4279x; 1.2228x over previous
//
#include <hip/hip_runtime.h>

typedef unsigned short u16;
typedef unsigned int u32;
typedef __attribute__((ext_vector_type(8))) short bf16x8;
typedef __attribute__((ext_vector_type(4))) float f32x4;

__device__ __forceinline__ float bf_lo(u32 u){ return __uint_as_float(u << 16); }
__device__ __forceinline__ float bf_hi(u32 u){ return __uint_as_float(u & 0xffff0000u); }
__device__ __forceinline__ float bf2f(u16 v){ return __uint_as_float((u32)v << 16); }
__device__ __forceinline__ u16 f2bf(float f){
    u32 u = __float_as_uint(f);
    u32 r = (u + 0x7fffu + ((u >> 16) & 1u)) >> 16;
    return (u16)r;
}
__device__ __forceinline__ u32 pack2(float a, float b){
    return (u32)f2bf(a) | ((u32)f2bf(b) << 16);
}

// ======== fused: hist3+rank || weight-fragment pre-swizzle || ntgemm_M || ntgemm_H ========
// Weight fragment layout (per 128x128 matrix, 16384 bf16):
//   idx(w,t,q,quad,ln16,j) = ((((w*2+t)*4+q)*4+quad)*16+ln16)*8 + j
//   element = W[(q*32+quad*8+j)*128 + (w*32+t*16+ln16)]
__global__ __launch_bounds__(256) void fusedA_kernel(
    const int* __restrict__ d0, const int* __restrict__ d1, const int* __restrict__ d2,
    int* __restrict__ rk0, int* __restrict__ rk1, int* __restrict__ rk2,
    int E0, int E1, int E2, int b0, int b1, int b2, int n0, int n1, int n2,
    int* __restrict__ cnt, int h0, int h1, int h2,
    const float* __restrict__ Wf0, const float* __restrict__ Wf1,
    const float* __restrict__ Wf2, const float* __restrict__ Wf3,
    const float* __restrict__ Wf4, const float* __restrict__ Wf5,
    u16* __restrict__ WF,
    const float* __restrict__ Xm, const float* __restrict__ Wm,
    const float* __restrict__ bm, u16* __restrict__ Tm, int NM,
    const float* __restrict__ Xh, const float* __restrict__ Wh,
    const float* __restrict__ bh, u16* __restrict__ Th, int NH,
    int gm, int gh)
{
    int bid = blockIdx.x;
    int HB = h0 + h1 + h2;
    if (bid < HB){
        int t, lb;
        if (bid < h0){ t = 0; lb = bid; }
        else if (bid < h0 + h1){ t = 1; lb = bid - h0; }
        else { t = 2; lb = bid - h0 - h1; }
        const int* d = t == 0 ? d0 : (t == 1 ? d1 : d2);
        int* rk = t == 0 ? rk0 : (t == 1 ? rk1 : rk2);
        int E = t == 0 ? E0 : (t == 1 ? E1 : E2);
        int b = t == 0 ? b0 : (t == 1 ? b1 : b2);
        int n = t == 0 ? n0 : (t == 1 ? n1 : n2);
        int i = lb * 256 + threadIdx.x;
        if (i < E){
            int x = d[i];
            if ((unsigned)x < (unsigned)n) rk[i] = atomicAdd(&cnt[b + x], 1);
        }
        return;
    }
    bid -= HB;
    if (bid < 6){
        const float* W = bid == 0 ? Wf0 : bid == 1 ? Wf1 : bid == 2 ? Wf2 :
                         bid == 3 ? Wf3 : bid == 4 ? Wf4 : Wf5;
        u16* dst = WF + (size_t)bid * 16384;
        #pragma unroll 4
        for (int k = 0; k < 64; ++k){
            int i = k * 256 + threadIdx.x;
            int j   = i & 7;
            int l16 = (i >> 3) & 15;
            int qd  = (i >> 7) & 3;
            int q   = (i >> 9) & 3;
            int tt  = (i >> 11) & 1;
            int w   = (i >> 12) & 3;
            dst[i] = f2bf(W[(q * 32 + qd * 8 + j) * 128 + (w * 32 + tt * 16 + l16)]);
        }
        return;
    }
    bid -= 6;
    const float *A, *W, *bias; u16* C; int N, lgrid, lbid;
    if (bid < gm){ A = Xm; W = Wm; bias = bm; C = Tm; N = NM; lgrid = gm; lbid = bid; }
    else         { A = Xh; W = Wh; bias = bh; C = Th; N = NH; lgrid = gh; lbid = bid - gm; }

    int tid = threadIdx.x;
    int wave = tid >> 6, lane = tid & 63;
    int colHalf = wave & 1;
    int ln16 = lane & 15, quad = lane >> 4;

    bf16x8 Bfrag[4][4];
    #pragma unroll
    for (int t = 0; t < 4; ++t){
        int col = colHalf * 64 + t * 16 + ln16;
        #pragma unroll
        for (int q = 0; q < 4; ++q){
            bf16x8 f;
            #pragma unroll
            for (int j = 0; j < 8; ++j)
                f[j] = (short)f2bf(W[(q * 32 + quad * 8 + j) * 128 + col]);
            Bfrag[t][q] = f;
        }
    }
    float bv[4];
    #pragma unroll
    for (int t = 0; t < 4; ++t)
        bv[t] = bias[colHalf * 64 + t * 16 + ln16];

    int rowBlocks = (N + 15) >> 4;
    for (int rb = lbid * 2 + (wave >> 1); rb < rowBlocks; rb += lgrid * 2){
        int row0 = rb * 16;
        int ar = row0 + ln16; if (ar > N - 1) ar = N - 1;
        const float* Arow = A + (size_t)ar * 128 + quad * 8;
        bf16x8 Af[4];
        #pragma unroll
        for (int q = 0; q < 4; ++q){
            f32x4 lo = *(const f32x4*)(Arow + q * 32);
            f32x4 hi = *(const f32x4*)(Arow + q * 32 + 4);
            bf16x8 f;
            #pragma unroll
            for (int j = 0; j < 4; ++j){ f[j] = (short)f2bf(lo[j]); f[4+j] = (short)f2bf(hi[j]); }
            Af[q] = f;
        }
        f32x4 acc[4];
        #pragma unroll
        for (int t = 0; t < 4; ++t) acc[t] = (f32x4){bv[t], bv[t], bv[t], bv[t]};
        #pragma unroll
        for (int q = 0; q < 4; ++q)
            #pragma unroll
            for (int t = 0; t < 4; ++t)
                acc[t] = __builtin_amdgcn_mfma_f32_16x16x32_bf16(Af[q], Bfrag[t][q], acc[t], 0, 0, 0);
        #pragma unroll
        for (int t = 0; t < 4; ++t){
            int col = colHalf * 64 + t * 16 + ln16;
            #pragma unroll
            for (int r = 0; r < 4; ++r){
                int row = row0 + quad * 4 + r;
                if (row < N) C[(size_t)row * 128 + col] = f2bf(acc[t][r]);
            }
        }
    }
}

// ---------------- 3-phase device-wide exclusive scan ----------------
__global__ __launch_bounds__(256) void scan_blocks_kernel(
    const int* __restrict__ cnt, int n, int* __restrict__ off, int* __restrict__ part)
{
    __shared__ int lds[256];
    int tid = threadIdx.x;
    int base = blockIdx.x * 2048 + tid * 8;
    int v[8]; int s = 0;
    #pragma unroll
    for (int j = 0; j < 8; ++j){
        int idx = base + j;
        int c = (idx < n) ? cnt[idx] : 0;
        v[j] = s; s += c;
    }
    lds[tid] = s;
    __syncthreads();
    for (int d = 1; d < 256; d <<= 1){
        int t = (tid >= d) ? lds[tid - d] : 0;
        __syncthreads();
        lds[tid] += t;
        __syncthreads();
    }
    int thrBase = (tid > 0) ? lds[tid - 1] : 0;
    if (tid == 255) part[blockIdx.x] = lds[255];
    #pragma unroll
    for (int j = 0; j < 8; ++j){
        int idx = base + j;
        if (idx < n) off[idx] = thrBase + v[j];
    }
}

__global__ __launch_bounds__(128) void scan_part_kernel(
    int* __restrict__ part, int np, int* __restrict__ total_slot)
{
    __shared__ int lds[128];
    int tid = threadIdx.x;
    lds[tid] = (tid < np) ? part[tid] : 0;
    __syncthreads();
    for (int d = 1; d < 128; d <<= 1){
        int t = (tid >= d) ? lds[tid - d] : 0;
        __syncthreads();
        lds[tid] += t;
        __syncthreads();
    }
    if (tid < np) part[tid] = (tid > 0) ? lds[tid - 1] : 0;
    if (tid == 0) *total_slot = lds[np - 1 < 0 ? 0 : np - 1];
}

__global__ __launch_bounds__(256) void scan_add_kernel(
    int* __restrict__ off, const int* __restrict__ part, int n)
{
    int i = blockIdx.x * 256 + threadIdx.x;
    if (i < n) off[i] += part[i >> 11];
}

// ===== atomic-free fill: p = off[dst] + precomputed rank =====
__global__ __launch_bounds__(256) void fill3_kernel(
    const int* __restrict__ s0, const int* __restrict__ s1, const int* __restrict__ s2,
    const int* __restrict__ d0, const int* __restrict__ d1, const int* __restrict__ d2,
    const int* __restrict__ rk0, const int* __restrict__ rk1, const int* __restrict__ rk2,
    int E0, int E1, int E2, int b0, int b1, int b2, int n0, int n1, int n2,
    const int* __restrict__ off, int* __restrict__ slot)
{
    int t = blockIdx.y;
    int i = blockIdx.x * 256 + threadIdx.x;
    const int* sp = t == 0 ? s0 : (t == 1 ? s1 : s2);
    const int* dp = t == 0 ? d0 : (t == 1 ? d1 : d2);
    const int* rk = t == 0 ? rk0 : (t == 1 ? rk1 : rk2);
    int E = t == 0 ? E0 : (t == 1 ? E1 : E2);
    int b = t == 0 ? b0 : (t == 1 ? b1 : b2);
    int n = t == 0 ? n0 : (t == 1 ? n1 : n2);
    if (i < E){
        int x = dp[i];
        if ((unsigned)x < (unsigned)n){
            slot[off[b + x] + rk[i]] = sp[i];
        }
    }
}

// ===== dedicated high-occupancy gather: 1 wave per (dst,edge-type) row =====
// Row id layout: [0,NM)=mm (src T_M), [NM,2NM)=hm (src T_H), [2NM,2NM+NH)=mh (src T_M).
// Each lane owns 2 columns (one u32 = 2 bf16). Output: mean rows, bf16-packed.
__global__ __launch_bounds__(256) void gather3_kernel(
    const u16* __restrict__ TM, const u16* __restrict__ TH,
    const int* __restrict__ off, const int* __restrict__ slot,
    u32* __restrict__ AGGM, u32* __restrict__ AGGH, int NM, int NH)
{
    int n3 = 2 * NM + NH;
    int wid = (int)((blockIdx.x * 256u + threadIdx.x) >> 6);
    int lane = threadIdx.x & 63;
    int nw = (gridDim.x * 256) >> 6;

    for (int id = wid; id < n3; id += nw){
        int b = off[id], e = off[id + 1];
        int deg = e - b;
        const u16* Tsrc; int nsrc;
        if (id < NM){ Tsrc = TM; nsrc = NM; }
        else if (id < 2 * NM){ Tsrc = TH; nsrc = NH; }
        else { Tsrc = TM; nsrc = NM; }

        int take = deg < 64 ? deg : 64;
        int ms = 0;
        if (lane < take){
            ms = slot[b + lane];
            if ((unsigned)ms >= (unsigned)nsrc) ms = 0;
        }

        float a0=0.f,a1=0.f,b0f=0.f,b1f=0.f,c0=0.f,c1=0.f,d0f=0.f,d1f=0.f;
        float e0=0.f,e1=0.f,f0=0.f,f1=0.f,g0=0.f,g1=0.f,h0=0.f,h1=0.f;
        int j = 0;
        for (; j + 8 <= take; j += 8){
            int i0 = __shfl(ms, j);     int i1 = __shfl(ms, j + 1);
            int i2 = __shfl(ms, j + 2); int i3 = __shfl(ms, j + 3);
            int i4 = __shfl(ms, j + 4); int i5 = __shfl(ms, j + 5);
            int i6 = __shfl(ms, j + 6); int i7 = __shfl(ms, j + 7);
            u32 u0 = *(const u32*)(Tsrc + (size_t)i0 * 128 + lane * 2);
            u32 u1 = *(const u32*)(Tsrc + (size_t)i1 * 128 + lane * 2);
            u32 u2 = *(const u32*)(Tsrc + (size_t)i2 * 128 + lane * 2);
            u32 u3 = *(const u32*)(Tsrc + (size_t)i3 * 128 + lane * 2);
            u32 u4 = *(const u32*)(Tsrc + (size_t)i4 * 128 + lane * 2);
            u32 u5 = *(const u32*)(Tsrc + (size_t)i5 * 128 + lane * 2);
            u32 u6 = *(const u32*)(Tsrc + (size_t)i6 * 128 + lane * 2);
            u32 u7 = *(const u32*)(Tsrc + (size_t)i7 * 128 + lane * 2);
            a0 += bf_lo(u0); a1 += bf_hi(u0);
            b0f += bf_lo(u1); b1f += bf_hi(u1);
            c0 += bf_lo(u2); c1 += bf_hi(u2);
            d0f += bf_lo(u3); d1f += bf_hi(u3);
            e0 += bf_lo(u4); e1 += bf_hi(u4);
            f0 += bf_lo(u5); f1 += bf_hi(u5);
            g0 += bf_lo(u6); g1 += bf_hi(u6);
            h0 += bf_lo(u7); h1 += bf_hi(u7);
        }
        for (; j + 4 <= take; j += 4){
            int i0 = __shfl(ms, j);     int i1 = __shfl(ms, j + 1);
            int i2 = __shfl(ms, j + 2); int i3 = __shfl(ms, j + 3);
            u32 u0 = *(const u32*)(Tsrc + (size_t)i0 * 128 + lane * 2);
            u32 u1 = *(const u32*)(Tsrc + (size_t)i1 * 128 + lane * 2);
            u32 u2 = *(const u32*)(Tsrc + (size_t)i2 * 128 + lane * 2);
            u32 u3 = *(const u32*)(Tsrc + (size_t)i3 * 128 + lane * 2);
            a0 += bf_lo(u0); a1 += bf_hi(u0);
            b0f += bf_lo(u1); b1f += bf_hi(u1);
            c0 += bf_lo(u2); c1 += bf_hi(u2);
            d0f += bf_lo(u3); d1f += bf_hi(u3);
        }
        for (; j < take; ++j){
            int i0 = __shfl(ms, j);
            u32 u0 = *(const u32*)(Tsrc + (size_t)i0 * 128 + lane * 2);
            a0 += bf_lo(u0); a1 += bf_hi(u0);
        }
        for (int j2 = b + 64; j2 < e; ++j2){
            int i0 = slot[j2];
            if ((unsigned)i0 >= (unsigned)nsrc) i0 = 0;
            u32 u0 = *(const u32*)(Tsrc + (size_t)i0 * 128 + lane * 2);
            a0 += bf_lo(u0); a1 += bf_hi(u0);
        }
        float s0 = ((a0 + b0f) + (c0 + d0f)) + ((e0 + f0) + (g0 + h0));
        float s1 = ((a1 + b1f) + (c1 + d1f)) + ((e1 + f1) + (g1 + h1));
        float inv = 1.0f / (float)(deg < 1 ? 1 : deg);
        u32 pv = pack2(s0 * inv, s1 * inv);
        if (id < 2 * NM) AGGM[(size_t)id * 64 + lane] = pv;
        else             AGGH[(size_t)(id - 2 * NM) * 64 + lane] = pv;
    }
}

// ===== streaming GEMM + L2-norm + edge-type combine + residual + LayerNorm =====
// Persistent weight fragments in registers (from pre-swizzled WF), A-fragments
// read directly from AGG (bf16 rows) and Tdst.
template<int NT>
__global__ __launch_bounds__(256) void gemmln_kernel(
    const u32* __restrict__ AG1, const u32* __restrict__ AG2,
    const u16* __restrict__ Tdst,
    const u16* __restrict__ WFl1, const u16* __restrict__ WFr1, const float* __restrict__ bl1,
    const u16* __restrict__ WFl2, const u16* __restrict__ WFr2, const float* __restrict__ bl2,
    const float* __restrict__ g, const float* __restrict__ be,
    float* __restrict__ outp, int N, float scale)
{
    __shared__ float redN[NT][4][16];   // per-edge-type sum-of-squares partials
    __shared__ float redS[2][4][16];    // LN sum / sumsq partials

    int tid = threadIdx.x;
    int wave = tid >> 6, lane = tid & 63;
    int ln16 = lane & 15, quad = lane >> 4;

    const u32* AG[2] = {AG1, AG2};
    const u16* WFl[2] = {WFl1, WFl2};
    const u16* WFr[2] = {WFr1, WFr2};
    const float* bls[2] = {bl1, bl2};

    bf16x8 BL[NT][2][4], BR[NT][2][4];
    float bv[NT][2];
    #pragma unroll
    for (int et = 0; et < NT; ++et){
        #pragma unroll
        for (int t = 0; t < 2; ++t){
            bv[et][t] = bls[et][wave * 32 + t * 16 + ln16];
            #pragma unroll
            for (int q = 0; q < 4; ++q){
                int fo = ((((wave * 2 + t) * 4 + q) * 4 + quad) * 16 + ln16) * 8;
                BL[et][t][q] = *(const bf16x8*)(WFl[et] + fo);
                BR[et][t][q] = *(const bf16x8*)(WFr[et] + fo);
            }
        }
    }
    float gv[2], bev[2];
    #pragma unroll
    for (int t = 0; t < 2; ++t){
        int col = wave * 32 + t * 16 + ln16;
        gv[t] = g[col]; bev[t] = be[col];
    }

    int tiles = (N + 15) >> 4;
    for (int tile = blockIdx.x; tile < tiles; tile += gridDim.x){
        int row0 = tile * 16;
        int ar = row0 + ln16; if (ar > N - 1) ar = N - 1;
        const u16* Ar2 = Tdst + (size_t)ar * 128 + quad * 8;

        f32x4 acc[NT][2];
        #pragma unroll
        for (int et = 0; et < NT; ++et)
            #pragma unroll
            for (int t = 0; t < 2; ++t)
                acc[et][t] = (f32x4){bv[et][t], bv[et][t], bv[et][t], bv[et][t]};

        #pragma unroll
        for (int q = 0; q < 4; ++q){
            bf16x8 afr = *(const bf16x8*)(Ar2 + q * 32);
            #pragma unroll
            for (int et = 0; et < NT; ++et){
                bf16x8 afl = *(const bf16x8*)(AG[et] + (size_t)ar * 64 + q * 16 + quad * 4);
                #pragma unroll
                for (int t = 0; t < 2; ++t){
                    acc[et][t] = __builtin_amdgcn_mfma_f32_16x16x32_bf16(afl, BL[et][t][q], acc[et][t], 0, 0, 0);
                    acc[et][t] = __builtin_amdgcn_mfma_f32_16x16x32_bf16(afr, BR[et][t][q], acc[et][t], 0, 0, 0);
                }
            }
        }

        // ---- per-edge-type row sum-of-squares (cross-wave) ----
        #pragma unroll
        for (int et = 0; et < NT; ++et){
            #pragma unroll
            for (int r = 0; r < 4; ++r){
                float s = acc[et][0][r] * acc[et][0][r] + acc[et][1][r] * acc[et][1][r];
                #pragma unroll
                for (int m = 1; m < 16; m <<= 1) s += __shfl_xor(s, m);
                if (ln16 == 0) redN[et][wave][quad * 4 + r] = s;
            }
        }
        __syncthreads();

        // ---- norm-scale, residual add, LN partial sums ----
        float yv[2][4];
        float lsum[4], lsq[4];
        #pragma unroll
        for (int r = 0; r < 4; ++r){
            int r16 = quad * 4 + r;
            int row = row0 + r16;
            int crow = row < N ? row : N - 1;
            float sc[NT];
            #pragma unroll
            for (int et = 0; et < NT; ++et){
                float tot = redN[et][0][r16] + redN[et][1][r16] + redN[et][2][r16] + redN[et][3][r16];
                sc[et] = scale / fmaxf(sqrtf(tot), 1e-12f);
            }
            float s1v = 0.f, s2v = 0.f;
            #pragma unroll
            for (int t = 0; t < 2; ++t){
                int col = wave * 32 + t * 16 + ln16;
                float y = bf2f(Tdst[(size_t)crow * 128 + col]);
                #pragma unroll
                for (int et = 0; et < NT; ++et) y += acc[et][t][r] * sc[et];
                yv[t][r] = y;
                s1v += y; s2v += y * y;
            }
            #pragma unroll
            for (int m = 1; m < 16; m <<= 1){ s1v += __shfl_xor(s1v, m); s2v += __shfl_xor(s2v, m); }
            lsum[r] = s1v; lsq[r] = s2v;
        }
        if (ln16 == 0){
            #pragma unroll
            for (int r = 0; r < 4; ++r){
                redS[0][wave][quad * 4 + r] = lsum[r];
                redS[1][wave][quad * 4 + r] = lsq[r];
            }
        }
        __syncthreads();

        // ---- final LayerNorm write ----
        #pragma unroll
        for (int r = 0; r < 4; ++r){
            int r16 = quad * 4 + r;
            int row = row0 + r16;
            if (row >= N) continue;
            float S1 = redS[0][0][r16] + redS[0][1][r16] + redS[0][2][r16] + redS[0][3][r16];
            float S2 = redS[1][0][r16] + redS[1][1][r16] + redS[1][2][r16] + redS[1][3][r16];
            float mean = S1 * (1.0f / 128.0f);
            float var = S2 * (1.0f / 128.0f) - mean * mean;
            float rstd = rsqrtf(var + 1e-5f);
            #pragma unroll
            for (int t = 0; t < 2; ++t){
                int col = wave * 32 + t * 16 + ln16;
                outp[(size_t)row * 128 + col] = (yv[t][r] - mean) * rstd * gv[t] + bev[t];
            }
        }
        __syncthreads();
    }
}

extern "C" void kernel_launch(void* const* d_in, const int* in_sizes, int n_in,
                              void* d_out, int out_size, void* d_ws, size_t ws_size,
                              hipStream_t stream) {
    const float* xm    = (const float*)d_in[0];
    const float* xh    = (const float*)d_in[1];
    const float* Wnt_m = (const float*)d_in[2];  const float* bnt_m = (const float*)d_in[3];
    const float* Wnt_h = (const float*)d_in[4];  const float* bnt_h = (const float*)d_in[5];
    const float* Wl_mm = (const float*)d_in[6];  const float* bl_mm = (const float*)d_in[7];
    const float* Wr_mm = (const float*)d_in[8];
    const float* Wl_mh = (const float*)d_in[9];  const float* bl_mh = (const float*)d_in[10];
    const float* Wr_mh = (const float*)d_in[11];
    const float* Wl_hm = (const float*)d_in[12]; const float* bl_hm = (const float*)d_in[13];
    const float* Wr_hm = (const float*)d_in[14];
    const float* g_m   = (const float*)d_in[15]; const float* be_m  = (const float*)d_in[16];
    const float* g_h   = (const float*)d_in[17]; const float* be_h  = (const float*)d_in[18];
    const int* ei_mm = (const int*)d_in[19];
    const int* ei_mh = (const int*)d_in[20];
    const int* ei_hm = (const int*)d_in[21];

    const int D = 128;
    const int NM = in_sizes[0] / D;
    const int NH = in_sizes[1] / D;
    const int E1 = in_sizes[19] / 2;   // mm
    const int E2 = in_sizes[20] / 2;   // mh
    const int E3 = in_sizes[21] / 2;   // hm
    const int Esum = E1 + E2 + E3;
    const int n3 = 2 * NM + NH;        // type0: mm->M, type1: hm->M, type2: mh->H

    char* ws = (char*)d_ws;
    size_t woff = 0;
    auto alloc = [&](size_t bytes) -> void* {
        void* p = ws + woff;
        woff += (bytes + 255) & ~(size_t)255;
        return p;
    };
    u16* T_M   = (u16*)alloc((size_t)NM * D * 2);
    u16* T_H   = (u16*)alloc((size_t)NH * D * 2);
    int* CNT3  = (int*)alloc((size_t)n3 * 4);
    int* OFF3  = (int*)alloc((size_t)(n3 + 1) * 4);
    int* SLOT3 = (int*)alloc((size_t)Esum * 4);
    int* PART  = (int*)alloc(1024 * 4);
    u16* WF    = (u16*)alloc((size_t)6 * 16384 * 2);   // pre-swizzled bf16 weights
    u32* AGGM  = (u32*)alloc((size_t)2 * NM * 64 * 4); // mean-agg rows for M-dst (mm,hm)
    if (woff > ws_size) return;

    // d_out staging: RANK3 (consumed by fill3), then AGGH (consumed by gemmln<1>
    // before gemmln<2> overwrites the region with OUT_M).
    int* RANK3 = (int*)d_out;
    int* rk0 = RANK3, *rk1 = RANK3 + E1, *rk2 = RANK3 + E1 + E3;
    u32* AGGH = (u32*)d_out;

    float* OUT_M = (float*)d_out;
    float* OUT_H = (float*)d_out + (size_t)NM * D;

    const int b0 = 0, b1 = NM, b2 = 2 * NM;
    const int h0 = (E1 + 255) / 256, h1 = (E3 + 255) / 256, h2 = (E2 + 255) / 256;
    const int gm = 1024, gh = 1024;
    int Emax = E1 > E2 ? E1 : E2; if (E3 > Emax) Emax = E3;
    const dim3 egrid((Emax + 255) / 256, 3);
    const int scanBlocks = (n3 + 2047) / 2048;

    hipMemsetAsync(CNT3, 0, (size_t)n3 * 4, stream);

    fusedA_kernel<<<h0 + h1 + h2 + 6 + gm + gh, 256, 0, stream>>>(
        ei_mm + E1, ei_hm + E3, ei_mh + E2,
        rk0, rk1, rk2,
        E1, E3, E2, b0, b1, b2, NM, NM, NH, CNT3, h0, h1, h2,
        Wl_mm, Wr_mm, Wl_hm, Wr_hm, Wl_mh, Wr_mh, WF,
        xm, Wnt_m, bnt_m, T_M, NM,
        xh, Wnt_h, bnt_h, T_H, NH, gm, gh);

    scan_blocks_kernel<<<scanBlocks, 256, 0, stream>>>(CNT3, n3, OFF3, PART);
    scan_part_kernel<<<1, 128, 0, stream>>>(PART, scanBlocks, OFF3 + n3);
    scan_add_kernel<<<(n3 + 255) / 256, 256, 0, stream>>>(OFF3, PART, n3);
    fill3_kernel<<<egrid, 256, 0, stream>>>(
        ei_mm, ei_hm, ei_mh,
        ei_mm + E1, ei_hm + E3, ei_mh + E2,
        rk0, rk1, rk2,
        E1, E3, E2, b0, b1, b2, NM, NM, NH, OFF3, SLOT3);

    // high-occupancy gather for all 3 edge types (1 wave per dst row)
    gather3_kernel<<<2048, 256, 0, stream>>>(
        T_M, T_H, OFF3, SLOT3, AGGM, AGGH, NM, NH);

    // H first (AGGH lives in d_out where OUT_M will go)
    gemmln_kernel<1><<<1024, 256, 0, stream>>>(
        AGGH, nullptr, T_H,
        WF + 4 * 16384, WF + 5 * 16384, bl_mh,
        nullptr, nullptr, nullptr,
        g_h, be_h, OUT_H, NH, 1.0f);
    gemmln_kernel<2><<<1024, 256, 0, stream>>>(
        AGGM, AGGM + (size_t)NM * 64, T_M,
        WF + 0 * 16384, WF + 1 * 16384, bl_mm,
        WF + 2 * 16384, WF + 3 * 16384, bl_hm,
        g_m, be_m, OUT_M, NM, 0.5f);
}